// Round 5
// baseline (500.501 us; speedup 1.0000x reference)
//
#include <hip/hip_runtime.h>
#include <hip/hip_bf16.h>
#include <cmath>

// Problem constants
#define Bq   4
#define Lq   4096
#define Wq   2048
#define Hq   8
#define Mq   (Bq*Lq)        // 16384 rows
#define RCH  128            // rows per chunk (8 waves x 16 rows)
#define NCH  (Lq/RCH)       // 32 chunks per sequence

typedef __bf16 bf16;
typedef __attribute__((ext_vector_type(8))) __bf16 bf16x8;
typedef __attribute__((ext_vector_type(4))) float  f32x4;

// ---- workspace layout (bytes) ----
#define WS_WT    0                               // bf16 [2][8][256][256] = 2 MiB (n-major)
#define WS_C     (2*8*256*256*2)                 // float [2048]

// ---------------- K0: weight transpose/cast (LDS tiled) + c vector ----------------
__global__ __launch_bounds__(256) void prep2(const float* __restrict__ ig_w,
                                             const float* __restrict__ ag_w,
                                             const float* __restrict__ a_param,
                                             bf16* __restrict__ wt, float* __restrict__ c_arr) {
    __shared__ float t[64*65];
    int bid = blockIdx.x;                 // 256 blocks: [g:1][h:3][nt:2][kt:2]
    int kt = bid & 3, nt = (bid >> 2) & 3, h = (bid >> 4) & 7, g = bid >> 7;
    const float* src = g ? ag_w : ig_w;
    int rr = threadIdx.x >> 6, cc = threadIdx.x & 63;
#pragma unroll
    for (int p = 0; p < 16; p++) {
        int kl = p*4 + rr;
        t[kl*65 + cc] = src[h*65536 + (kt*64 + kl)*256 + nt*64 + cc];  // coalesced read
    }
    if (bid < 8) {
        float ap = a_param[bid*256 + threadIdx.x];
        c_arr[bid*256 + threadIdx.x] = 8.0f * log1pf(__expf(ap));      // 8*softplus
    }
    __syncthreads();
#pragma unroll
    for (int p = 0; p < 16; p++) {
        int nl = p*4 + rr;
        wt[((size_t)((g*8 + h)*256) + nt*64 + nl)*256 + kt*64 + cc] = (bf16)t[cc*65 + nl]; // coalesced write
    }
}

// ---------------- K1: fused persistent-chain RG-LRU (16-ch stripes, 2 blocks/CU) ----
// 512 blocks = (stripe s:16)*(b:4)*(h:8), bid = s*32 + b*8 + h -> bid%8==h: the 16
// stripe-blocks of an (b,h) x-slab land on one XCD (round-robin) for L2 reuse.
// Each block owns 16 channels of one batch, walks 32 chunks of 128 rows.
// 2 blocks/CU (4 waves/SIMD): independent blocks share no barrier, so stall
// phases interleave -> latency hiding via TLP, not register pipelining.
// Per chunk (ONE barrier):
//   A: MFMA(xs regs x LDS weight frags) -> acc; issue next xs; gates in regs;
//      issue next xg/segpos.
//   B: in-lane 4-row scan; 2-step Kogge-Stone over quads via __shfl; write wave
//      aggregate to sg[parity].
//   BARRIER
//   C: 7-step cross-wave ladder from hc[parity] + sg[parity]; store y; wave 7
//      writes hc[!parity].
// Hazard audit (1 barrier valid): sg/hc are parity ping-ponged; a wave can only
// write parity p again after passing the NEXT barrier, and every wave's parity-p
// reads precede its next barrier arrival -> no overlap. Weight LDS is read-only
// after the init barrier.
__global__ __launch_bounds__(512, 4) void rglru_fused(
    const float* __restrict__ x, const int* __restrict__ segpos,
    const float* __restrict__ prev_h,
    const bf16* __restrict__ wt, const float* __restrict__ igb,
    const float* __restrict__ agb, const float* __restrict__ c_arr,
    float* __restrict__ out)
{
    __shared__ bf16x8 Wl[16*64];                 // [g*8+ks][lane] frags, 16 KB
    __shared__ float sgA[2][8][16], sgH[2][8][16];
    __shared__ float hc[2][16];

    const int tid = threadIdx.x;
    const int bid = blockIdx.x;
    const int h = bid & 7, b = (bid >> 3) & 3, s = bid >> 5;   // s: 0..15
    const int lane = tid & 63, wv = tid >> 6;
    const int l16 = lane & 15, quad = lane >> 4;
    const int wcol0 = h*256 + s*16;              // global channel base (16 wide)

    // ---- fill weight LDS in exact B-fragment order (one-time, 16 KB)
    for (int t = tid; t < 1024; t += 512) {
        int ln = t & 63, ks = (t >> 6) & 7, g = t >> 9;
        int n  = s*16 + (ln & 15);
        int k  = ks*32 + (ln >> 4)*8;
        Wl[t] = *(const bf16x8*)&wt[((size_t)((g*8 + h)*256 + n))*256 + k];
    }
    const int wf = wcol0 + l16;
    const float bxv = igb[wf], bav = agb[wf], ccv = c_arr[wf];
    if (tid < 16) hc[0][tid] = prev_h[b*Wq + wcol0 + tid];

    // fragment-layout x pointer: lane (l16,quad) -> row wv*16+l16, cols quad*8 (+ks*32)
    const float* xfrag = x + ((size_t)b*Lq + wv*16 + l16)*Wq + h*256 + quad*8;
    // gate-layout x pointer: lane (quad,l16) -> row wv*16+quad*4 (+r), col wcol0+l16
    const float* xgate = x + ((size_t)b*Lq + wv*16 + quad*4)*Wq + wcol0 + l16;
    const int*   spp   = segpos + wv*16 + quad*4;

    // ---- prologue: chunk-0 prefetch into registers
    float4 xs[16]; float xg[4]; int sp[4];
#pragma unroll
    for (int ks = 0; ks < 8; ks++) {
        xs[2*ks]   = *(const float4*)(xfrag + ks*32);
        xs[2*ks+1] = *(const float4*)(xfrag + ks*32 + 4);
    }
#pragma unroll
    for (int r = 0; r < 4; r++) {
        sp[r] = spp[r];
        xg[r] = xgate[(size_t)r*Wq];
    }
    __syncthreads();

    for (int c = 0; c < NCH; ++c) {
        const int cur = c & 1, nxt = cur ^ 1;
        const int cn  = (c < NCH-1) ? c+1 : c;

        // ---- phase A: MFMA against LDS weight fragments (N=16: one tile, 2 gates)
        f32x4 ax = (f32x4){0.f,0.f,0.f,0.f};
        f32x4 aa = (f32x4){0.f,0.f,0.f,0.f};
#pragma unroll
        for (int ks = 0; ks < 8; ks++) {
            float4 u0 = xs[2*ks], u1 = xs[2*ks+1];
            bf16x8 af;
            af[0]=(bf16)u0.x; af[1]=(bf16)u0.y; af[2]=(bf16)u0.z; af[3]=(bf16)u0.w;
            af[4]=(bf16)u1.x; af[5]=(bf16)u1.y; af[6]=(bf16)u1.z; af[7]=(bf16)u1.w;
            bf16x8 w0 = Wl[(0*8+ks)*64 + lane];   // ig
            bf16x8 w1 = Wl[(1*8+ks)*64 + lane];   // ag
            ax = __builtin_amdgcn_mfma_f32_16x16x32_bf16(af, w0, ax, 0,0,0);
            aa = __builtin_amdgcn_mfma_f32_16x16x32_bf16(af, w1, aa, 0,0,0);
        }
        {   // issue next-chunk fragment loads (xs regs dead after the converts above)
            const float* xp = xfrag + (size_t)cn*RCH*Wq;
#pragma unroll
            for (int ks = 0; ks < 8; ks++) {
                xs[2*ks]   = *(const float4*)(xp + ks*32);
                xs[2*ks+1] = *(const float4*)(xp + ks*32 + 4);
            }
        }

        // ---- gates in registers (acc layout == gate layout: row quad*4+r, col l16)
        float av[4], xn[4];
#pragma unroll
        for (int r = 0; r < 4; r++) {
            bool rst = (sp[r] == 0);
            float zx = ax[r] + bxv;
            float za = aa[r] + bav;
            float gx = __builtin_amdgcn_rcpf(1.f + __expf(-zx));
            float ga = __builtin_amdgcn_rcpf(1.f + __expf(-za));
            float a  = __expf(-ga * ccv);
            float mult = __builtin_amdgcn_sqrtf(fmaf(-a, a, 1.f)); // sqrt(1-a^2)
            if (rst) { a = 0.f; mult = 1.f; }
            av[r] = a;
            xn[r] = gx * mult * xg[r];
        }
        {   // issue next-chunk gate-side loads (xg/sp dead after gates)
            const float* xp = xgate + (size_t)cn*RCH*Wq;
            const int*   spn = spp + cn*RCH;
#pragma unroll
            for (int r = 0; r < 4; r++) {
                sp[r] = spn[r];
                xg[r] = xp[(size_t)r*Wq];
            }
        }

        // ---- phase B: in-register scan. 4 rows in-lane, Kogge-Stone over quads.
        float Pl[4], hl[4];
        float A = 1.f, hv = 0.f;
#pragma unroll
        for (int r = 0; r < 4; r++) {
            hv = fmaf(av[r], hv, xn[r]);
            A *= av[r];
            Pl[r] = A; hl[r] = hv;
        }
        // inclusive (A,H) scan over quad dim: compose(prev,cur) = (Ap*Ac, Ac*Hp+Hc)
        float Asc = A, Hsc = hv;
        float Apv = __shfl(Asc, (lane-16) & 63), Hpv = __shfl(Hsc, (lane-16) & 63);
        if (quad >= 1) { Hsc = fmaf(Asc, Hpv, Hsc); Asc *= Apv; }
        Apv = __shfl(Asc, (lane-32) & 63); Hpv = __shfl(Hsc, (lane-32) & 63);
        if (quad >= 2) { Hsc = fmaf(Asc, Hpv, Hsc); Asc *= Apv; }
        float Aex = __shfl(Asc, (lane-16) & 63), Hex = __shfl(Hsc, (lane-16) & 63); // exclusive
        if (quad == 0) { Aex = 1.f; Hex = 0.f; }
#pragma unroll
        for (int r = 0; r < 4; r++) {          // make rows wave-seg-relative
            hl[r] = fmaf(Pl[r], Hex, hl[r]);
            Pl[r] *= Aex;
        }
        if (quad == 3) { sgA[cur][wv][l16] = Asc; sgH[cur][wv][l16] = Hsc; }
        __syncthreads();

        // ---- phase C: cross-wave ladder + apply + store
        float h0 = hc[cur][l16];
#pragma unroll
        for (int w = 0; w < 7; w++)            // wave-uniform predicate: no divergence
            if (w < wv) h0 = fmaf(sgA[cur][w][l16], h0, sgH[cur][w][l16]);
        float* yp = out + ((size_t)b*Lq + (size_t)c*RCH + wv*16 + quad*4)*Wq + wcol0 + l16;
#pragma unroll
        for (int r = 0; r < 4; r++)
            yp[(size_t)r*Wq] = fmaf(Pl[r], h0, hl[r]);
        if (wv == 7 && quad == 3)
            hc[nxt][l16] = fmaf(Asc, h0, Hsc);  // block carry for next chunk
    }
    __syncthreads();
    if (tid < 16) out[(size_t)Mq*Wq + b*Wq + wcol0 + tid] = hc[NCH & 1][tid];  // last_h
}

extern "C" void kernel_launch(void* const* d_in, const int* in_sizes, int n_in,
                              void* d_out, int out_size, void* d_ws, size_t ws_size,
                              hipStream_t stream) {
    const float* x       = (const float*)d_in[0];
    const int*   segpos  = (const int*)  d_in[1];
    const float* prev_h  = (const float*)d_in[2];
    const float* ig_w    = (const float*)d_in[3];
    const float* ig_b    = (const float*)d_in[4];
    const float* ag_w    = (const float*)d_in[5];
    const float* ag_b    = (const float*)d_in[6];
    const float* a_param = (const float*)d_in[7];
    float* out = (float*)d_out;                    // [M*W] y then [B*W] last_h

    char* ws = (char*)d_ws;
    bf16*   wt    = (bf16*)  (ws + WS_WT);
    float*  c_arr = (float*) (ws + WS_C);

    prep2<<<256, 256, 0, stream>>>(ig_w, ag_w, a_param, wt, c_arr);
    rglru_fused<<<512, 512, 0, stream>>>(x, segpos, prev_h, wt, ig_b, ag_b, c_arr, out);
}